// Round 20
// baseline (227.969 us; speedup 1.0000x reference)
//
#include <hip/hip_runtime.h>
#include <hip/hip_bf16.h>
#include <stdint.h>
#include <math.h>

// Problem constants
#define NB      16
#define LL      1024
#define EE      512
#define NHEADS  8
#define DFF     2048
#define NLEVELS 10
#define NSCALES 11
#define BROWS   (NB * LL)       // 16384

typedef unsigned short u16;
typedef __attribute__((ext_vector_type(8))) short bf16x8;
typedef __attribute__((ext_vector_type(4))) float f32x4;

// ---------------- workspace layout (byte offsets) ----------------
static const size_t B_SRCBF = 0;
static const size_t B_LVLBF = 16777216;
static const size_t B_QKV   = 33538048;
static const size_t B_KVS   = 83869696;
static const size_t B_OBF   = 117391360;
static const size_t B_XPRE  = 134168576;
static const size_t B_OUTBF = 150945792;
static const size_t B_XBF   = 167723008;
static const size_t B_WBF   = 184500224;
static const size_t B_FFH   = 0;

// ---------------- helpers ----------------
__device__ __forceinline__ u16 f2bf(float x) {
    union { float f; uint32_t u; } c; c.f = x;
    uint32_t u = c.u + 0x7FFFu + ((c.u >> 16) & 1u);
    return (u16)(u >> 16);
}
__device__ __forceinline__ float bf2f(u16 v) {
    union { uint32_t u; float f; } c; c.u = ((uint32_t)v) << 16; return c.f;
}
__device__ __forceinline__ uint32_t addbf2(uint32_t a, uint32_t b) {
    float lo = bf2f((u16)(a & 0xFFFF)) + bf2f((u16)(b & 0xFFFF));
    float hi = bf2f((u16)(a >> 16))    + bf2f((u16)(b >> 16));
    return (uint32_t)f2bf(lo) | ((uint32_t)f2bf(hi) << 16);
}
__device__ __forceinline__ void ld8bf(const u16* p, float* f) {
    uint4 r = *(const uint4*)p;
    uint32_t ws[4] = { r.x, r.y, r.z, r.w };
    #pragma unroll
    for (int j = 0; j < 4; j++) {
        union { uint32_t u; float g; } lo, hi;
        lo.u = ws[j] << 16; hi.u = ws[j] & 0xFFFF0000u;
        f[2 * j] = lo.g; f[2 * j + 1] = hi.g;
    }
}
__device__ __forceinline__ void gload16(const u16* g, u16* l) {
    __builtin_amdgcn_global_load_lds(
        (const __attribute__((address_space(1))) void*)g,
        (__attribute__((address_space(3))) void*)l, 16, 0, 0);
}

// ---------------------------------------------------------------------------
// Fused cast kernel (unchanged).
// ---------------------------------------------------------------------------
__global__ void cast_all_kernel(const float* __restrict__ s0, const float* __restrict__ s1,
                                const float* __restrict__ s2, const float* __restrict__ s3,
                                const float* __restrict__ s4, const float* __restrict__ cw,
                                u16* __restrict__ d0, u16* __restrict__ d1,
                                u16* __restrict__ d2, u16* __restrict__ d3,
                                u16* __restrict__ d4, u16* __restrict__ dw)
{
    int bid = blockIdx.x;
    if (bid >= 11264) {
        int base = (bid - 11264) * 1024 + threadIdx.x * 4;
        #pragma unroll
        for (int j = 0; j < 4; j++) {
            int idx = base + j;
            int lvl = idx >> 13, rem = idx & 8191;
            int o = rem >> 7, ck = rem & 127;
            int k = ck >> 6, ci = ck & 63;
            dw[idx] = f2bf(cw[(lvl << 13) + (o << 7) + (ci << 1) + k]);
        }
        return;
    }
    const float* s; u16* d; int nt;
    if      (bid < 8192)  { s = s0; d = d0; nt = 2097152; }
    else if (bid < 8960)  { bid -= 8192;  s = s1; d = d1; nt = 196608; }
    else if (bid < 9216)  { bid -= 8960;  s = s2; d = d2; nt = 65536;  }
    else if (bid < 10240) { bid -= 9216;  s = s3; d = d3; nt = 262144; }
    else                  { bid -= 10240; s = s4; d = d4; nt = 262144; }
    int i = bid * 256 + threadIdx.x;
    if (i < nt) {
        float4 v = ((const float4*)s)[i];
        uint2 o;
        o.x = (uint32_t)f2bf(v.x) | ((uint32_t)f2bf(v.y) << 16);
        o.y = (uint32_t)f2bf(v.z) | ((uint32_t)f2bf(v.w) << 16);
        ((uint2*)d)[i] = o;
    }
}

// ---------------------------------------------------------------------------
// Conv chain body, 512-thread version (8 waves split fragments, f += 8).
// Uses the caller's LDS: BIG = lds[0..16383], MID = +16384, WB = +24576.
// One block per (n, head, quarter): bid = n*32 + h*4 + q, 512 blocks total.
// ---------------------------------------------------------------------------
__device__ __forceinline__ void conv_chain_body(
    u16* lds, const u16* __restrict__ src_bf, u16* __restrict__ lvl_bf,
    const u16* __restrict__ cw, const float* __restrict__ cb, int bid)
{
    u16* BIG = lds;            // 16384 u16
    u16* MID = lds + 16384;    // 8192 u16
    u16* WB  = lds + 24576;    // 8192 u16
    const int tid = threadIdx.x;
    const int l = tid & 63, w = tid >> 6;   // 8 waves
    const int q  = bid & 3;
    const int h  = (bid >> 2) & 7;
    const int n  = bid >> 5;

    // stage L1 input: 2048 chunks, 4 per thread
    {
        const u16* base = src_bf + ((size_t)n * 1024 + q * 256) * 512 + h * 64;
        #pragma unroll
        for (int j = 0; j < 4; j++) {
            int c = j * 512 + w * 64 + l;
            int row = c >> 3, lch = c & 7;
            int gch = lch ^ (row & 7);
            gload16(base + (size_t)row * 512 + gch * 8,
                    BIG + (size_t)(j * 512 + w * 64) * 8);
        }
    }

    const u16* IN = BIG;
    u16* OUTb = MID;
    int R = 128;
    int T = 512;
    size_t rowOff = 0;
    for (int lvl = 1; lvl <= 8; lvl++) {
        {   // stage weights: 1024 chunks, 2 per thread
            const u16* wsrc = cw + (size_t)(lvl - 1) * 8192;
            #pragma unroll
            for (int j = 0; j < 2; j++) {
                int c = j * 512 + w * 64 + l;
                int o = c >> 4, lch = c & 15;
                int gch = lch ^ (o & 7);
                gload16(wsrc + o * 128 + gch * 8, WB + (size_t)(j * 512 + w * 64) * 8);
            }
        }
        asm volatile("s_waitcnt vmcnt(0)" ::: "memory");
        __syncthreads();

        const int nrt = (R + 15) >> 4;
        const int maxil = 2 * R - 1;
        for (int f = w; f < nrt * 4; f += 8) {
            int rt = f >> 2, nc = f & 3;
            int o = nc * 16 + (l & 15);
            f32x4 acc = {0.f, 0.f, 0.f, 0.f};
            #pragma unroll
            for (int s = 0; s < 4; s++) {
                int il = 2 * (rt * 16 + (l & 15)) + (s >> 1);
                if (il > maxil) il = maxil;
                int ach = (((s & 1) * 4) + (l >> 4)) ^ (il & 7);
                bf16x8 av = *(const bf16x8*)(IN + il * 64 + ach * 8);
                int bch = (s * 4 + (l >> 4)) ^ (o & 7);
                bf16x8 bv = *(const bf16x8*)(WB + o * 128 + bch * 8);
                acc = __builtin_amdgcn_mfma_f32_16x16x32_bf16(av, bv, acc, 0, 0, 0);
            }
            float bb = cb[(lvl - 1) * 64 + o];
            #pragma unroll
            for (int reg = 0; reg < 4; reg++) {
                int rloc = rt * 16 + (l >> 4) * 4 + reg;
                if (rloc < R) {
                    float v = fmaxf(acc[reg] + bb, 0.f);
                    u16 b16 = f2bf(v);
                    lvl_bf[(rowOff + (size_t)n * T + (size_t)q * R + rloc) * 512 + h * 64 + o] = b16;
                    OUTb[rloc * 64 + (((o >> 3) ^ (rloc & 7)) << 3) + (o & 7)] = b16;
                }
            }
        }
        __syncthreads();
        const u16* tmp = IN; IN = OUTb; OUTb = (u16*)tmp;
        rowOff += (size_t)16 * T;
        T >>= 1; R >>= 1;
    }
}

// ---------------------------------------------------------------------------
// Conv tail (unchanged, 256 threads).
// ---------------------------------------------------------------------------
__global__ void conv_tail_kernel(u16* __restrict__ lvl_bf, const u16* __restrict__ cw,
                                 const float* __restrict__ cb)
{
    const int h = blockIdx.x & 7, n = blockIdx.x >> 3;
    const int tid = threadIdx.x;
    __shared__ float L8s[4][64];
    __shared__ float L9s[2][64];
    {
        int r = tid >> 6, c = tid & 63;
        L8s[r][c] = bf2f(lvl_bf[((size_t)16256 + n * 4 + r) * 512 + h * 64 + c]);
    }
    __syncthreads();
    if (tid < 128) {
        int t = tid >> 6, o = tid & 63;
        const u16* wr = cw + (size_t)8 * 8192 + o * 128;
        float acc = cb[8 * 64 + o];
        #pragma unroll
        for (int k = 0; k < 2; k++)
            #pragma unroll 16
            for (int ci = 0; ci < 64; ci++)
                acc += L8s[2 * t + k][ci] * bf2f(wr[k * 64 + ci]);
        acc = fmaxf(acc, 0.f);
        L9s[t][o] = acc;
        lvl_bf[((size_t)16320 + n * 2 + t) * 512 + h * 64 + o] = f2bf(acc);
    }
    __syncthreads();
    if (tid < 64) {
        int o = tid;
        const u16* wr = cw + (size_t)9 * 8192 + o * 128;
        float acc = cb[9 * 64 + o];
        #pragma unroll
        for (int k = 0; k < 2; k++)
            #pragma unroll 16
            for (int ci = 0; ci < 64; ci++)
                acc += L9s[k][ci] * bf2f(wr[k * 64 + ci]);
        acc = fmaxf(acc, 0.f);
        lvl_bf[((size_t)16352 + n) * 512 + h * 64 + o] = f2bf(acc);
    }
}

// ---------------------------------------------------------------------------
// v4 GEMM body (unchanged, round-13 proven).
// ---------------------------------------------------------------------------
__device__ __forceinline__ void gemm_v4_body(
    u16* lds,
    const u16* __restrict__ A, const u16* __restrict__ W,
    const float* __restrict__ bias, const u16* __restrict__ resb,
    u16* __restrict__ Cb, int M, int K, int N, int relu, int gx,
    int nwg, int bid)
{
    const int tid = threadIdx.x;
    const int l = tid & 63, w = tid >> 6;
    const int wm = w >> 1, wn = w & 1;

    const int q = nwg >> 3, r = nwg & 7;
    const int xcd = bid & 7, idx = bid >> 3;
    const int lin = (xcd < r ? xcd * (q + 1) : r * (q + 1) + (xcd - r) * q) + idx;
    const int by = lin / gx, bx = lin - by * gx;
    const int rowBase = by * 256, colBase = bx * 128;

    f32x4 acc[4][4];
    #pragma unroll
    for (int m = 0; m < 4; m++)
        #pragma unroll
        for (int n = 0; n < 4; n++) acc[m][n] = 0.f;

    const u16* gApt[2];
    const u16* gBpt;
    #pragma unroll
    for (int i = 0; i < 2; i++) {
        int G = i * 512 + tid;
        int row = G >> 2, p = G & 3;
        int c = p ^ ((row >> 1) & 3);
        int grow = rowBase + row; if (grow > M - 1) grow = M - 1;
        gApt[i] = A + (size_t)grow * K + c * 8;
    }
    {
        int G = tid;
        int row = G >> 2, p = G & 3;
        int c = p ^ ((row >> 1) & 3);
        gBpt = W + (size_t)(colBase + row) * K + c * 8;
    }

    const int NT = K >> 5;
    auto STAGE = [&](int tt, int buf) {
        const int kb = tt << 5;
        u16* dA = lds + buf * 12288;
        u16* dB = dA + 8192;
        gload16(gApt[0] + kb, dA + (size_t)(w * 64) * 8);
        gload16(gApt[1] + kb, dA + (size_t)(512 + w * 64) * 8);
        gload16(gBpt + kb, dB + (size_t)(w * 64) * 8);
    };
    STAGE(0, 0);
    if (NT > 1) STAGE(1, 1);

    int cbuf = 0, sbuf = 2;
    for (int t = 0; t < NT; ++t) {
        if (t + 1 < NT) asm volatile("s_waitcnt vmcnt(3)" ::: "memory");
        else            asm volatile("s_waitcnt vmcnt(0)" ::: "memory");
        __builtin_amdgcn_s_barrier();
        __builtin_amdgcn_sched_barrier(0);
        if (t + 2 < NT) STAGE(t + 2, sbuf);

        const u16* Ab = lds + cbuf * 12288;
        const u16* Bb = Ab + 8192;
        const int c = l >> 4;
        bf16x8 av[4], bv[4];
        #pragma unroll
        for (int fr = 0; fr < 4; fr++) {
            int row = wm * 64 + fr * 16 + (l & 15);
            av[fr] = *(const bf16x8*)(Ab + row * 32 + ((c ^ ((row >> 1) & 3)) * 8));
        }
        #pragma unroll
        for (int fc = 0; fc < 4; fc++) {
            int col = wn * 64 + fc * 16 + (l & 15);
            bv[fc] = *(const bf16x8*)(Bb + col * 32 + ((c ^ ((col >> 1) & 3)) * 8));
        }
        __builtin_amdgcn_s_setprio(1);
        #pragma unroll
        for (int m = 0; m < 4; m++)
            #pragma unroll
            for (int n = 0; n < 4; n++)
                acc[m][n] = __builtin_amdgcn_mfma_f32_16x16x32_bf16(av[m], bv[n], acc[m][n], 0, 0, 0);
        __builtin_amdgcn_s_setprio(0);

        cbuf = (cbuf == 2) ? 0 : cbuf + 1;
        sbuf = (sbuf == 2) ? 0 : sbuf + 1;
    }
    __builtin_amdgcn_s_barrier();
    __builtin_amdgcn_sched_barrier(0);

    const int cc = colBase + wn * 64 + (l & 15);
    float bs4[4];
    #pragma unroll
    for (int n = 0; n < 4; n++) bs4[n] = bias[cc + n * 16];

    u16* WS = lds + w * 2048;
    #pragma unroll
    for (int hh = 0; hh < 2; hh++) {
        #pragma unroll
        for (int mi = 0; mi < 2; mi++) {
            #pragma unroll
            for (int n = 0; n < 4; n++) {
                int colv = n * 16 + (l & 15);
                #pragma unroll
                for (int reg = 0; reg < 4; reg++) {
                    int rowh = mi * 16 + (l >> 4) * 4 + reg;
                    float v = acc[hh * 2 + mi][n][reg] + bs4[n];
                    if (relu) v = fmaxf(v, 0.f);
                    WS[rowh * 64 + (colv ^ (((rowh >> 2) & 3) << 4))] = f2bf(v);
                }
            }
        }
        asm volatile("s_waitcnt lgkmcnt(0)" ::: "memory");
        __builtin_amdgcn_sched_barrier(0);
        #pragma unroll
        for (int j = 0; j < 4; j++) {
            int rowh = (l >> 3) + 8 * j;
            int col8 = (l & 7) * 8;
            int colx = col8 ^ (((rowh >> 2) & 3) << 4);
            uint4 v = *(const uint4*)(WS + rowh * 64 + colx);
            int grow = rowBase + wm * 64 + hh * 32 + rowh;
            if (grow < M) {
                int gcol = colBase + wn * 64 + col8;
                if (resb) {
                    uint4 rb = *(const uint4*)&resb[(size_t)grow * N + gcol];
                    v.x = addbf2(v.x, rb.x);
                    v.y = addbf2(v.y, rb.y);
                    v.z = addbf2(v.z, rb.z);
                    v.w = addbf2(v.w, rb.w);
                }
                *(uint4*)(Cb + (size_t)grow * N + gcol) = v;
            }
        }
        asm volatile("s_waitcnt lgkmcnt(0)" ::: "memory");
    }
}

__global__ __launch_bounds__(512, 4)
void mfma_gemm(const u16* __restrict__ A, const u16* __restrict__ W,
               const float* __restrict__ bias, const u16* __restrict__ resb,
               u16* __restrict__ Cb, int M, int K, int N, int relu, int gx)
{
    __shared__ u16 lds[36864];
    gemm_v4_body(lds, A, W, bias, resb, Cb, M, K, N, relu, gx,
                 gridDim.x, blockIdx.x);
}

// Dual: blocks [0,512) -> conv chain (512 blocks: n*32+h*4+q), [512,1280) -> QKV.
__global__ __launch_bounds__(512, 4)
void conv_qkv_dual(const u16* __restrict__ src_bf, u16* __restrict__ lvl_bf,
                   const u16* __restrict__ cw, const float* __restrict__ cb,
                   const u16* __restrict__ inw, const float* __restrict__ inb,
                   u16* __restrict__ QKV)
{
    __shared__ u16 lds[36864];
    if ((int)blockIdx.x < 512)
        conv_chain_body(lds, src_bf, lvl_bf, cw, cb, blockIdx.x);
    else
        gemm_v4_body(lds, src_bf, inw, inb, nullptr, QKV, BROWS, EE, 1536, 0, 12,
                     768, blockIdx.x - 512);
}

// ---------------------------------------------------------------------------
// Attention (bf16 in/out) with XCD-chunked block swizzle (unchanged).
// ---------------------------------------------------------------------------
__global__ void attn_kernel(const u16* __restrict__ QKV, const u16* __restrict__ KVs,
                            u16* __restrict__ O)
{
    const int wv   = threadIdx.x >> 6;
    const int lane = threadIdx.x & 63;
    const int bswz = (blockIdx.x & 7) * (gridDim.x >> 3) + (blockIdx.x >> 3);
    const int b    = bswz * 4 + wv;
    const int h    = lane >> 3;
    const int d8   = lane & 7;
    const int n = b >> 10, pos = b & 1023;

    float q[8];
    ld8bf(QKV + (size_t)b * 1536 + h * 64 + d8 * 8, q);

    float sc[NSCALES];
    {
        float kk[8];
        ld8bf(QKV + (size_t)b * 1536 + 512 + h * 64 + d8 * 8, kk);
        float p = 0.f;
        #pragma unroll
        for (int j = 0; j < 8; j++) p += q[j] * kk[j];
        p += __shfl_xor(p, 1); p += __shfl_xor(p, 2); p += __shfl_xor(p, 4);
        sc[0] = p * 0.125f;
    }
    {
        int rowOff = 0;
        #pragma unroll
        for (int s = 1; s <= NLEVELS; s++) {
            int Ls = 1024 >> s;
            int row = rowOff + n * Ls + (pos >> s);
            float kk[8];
            ld8bf(KVs + (size_t)row * 1024 + h * 64 + d8 * 8, kk);
            float p = 0.f;
            #pragma unroll
            for (int j = 0; j < 8; j++) p += q[j] * kk[j];
            p += __shfl_xor(p, 1); p += __shfl_xor(p, 2); p += __shfl_xor(p, 4);
            sc[s] = p * 0.125f;
            rowOff += 16 * Ls;
        }
    }
    float m = sc[0];
    #pragma unroll
    for (int s = 1; s < NSCALES; s++) m = fmaxf(m, sc[s]);
    float sum = 0.f;
    #pragma unroll
    for (int s = 0; s < NSCALES; s++) { sc[s] = __expf(sc[s] - m); sum += sc[s]; }
    float inv = 1.f / sum;

    float o[8] = {};
    {
        float vv[8];
        ld8bf(QKV + (size_t)b * 1536 + 1024 + h * 64 + d8 * 8, vv);
        float a = sc[0] * inv;
        #pragma unroll
        for (int j = 0; j < 8; j++) o[j] += a * vv[j];
    }
    {
        int rowOff = 0;
        #pragma unroll
        for (int s = 1; s <= NLEVELS; s++) {
            int Ls = 1024 >> s;
            int row = rowOff + n * Ls + (pos >> s);
            float vv[8];
            ld8bf(KVs + (size_t)row * 1024 + 512 + h * 64 + d8 * 8, vv);
            float a = sc[s] * inv;
            #pragma unroll
            for (int j = 0; j < 8; j++) o[j] += a * vv[j];
            rowOff += 16 * Ls;
        }
    }
    uint4 pk;
    pk.x = (uint32_t)f2bf(o[0]) | ((uint32_t)f2bf(o[1]) << 16);
    pk.y = (uint32_t)f2bf(o[2]) | ((uint32_t)f2bf(o[3]) << 16);
    pk.z = (uint32_t)f2bf(o[4]) | ((uint32_t)f2bf(o[5]) << 16);
    pk.w = (uint32_t)f2bf(o[6]) | ((uint32_t)f2bf(o[7]) << 16);
    *(uint4*)(O + (size_t)b * 512 + h * 64 + d8 * 8) = pk;
}

// ---------------------------------------------------------------------------
// LayerNorm over E=512, bf16 input (unchanged).
// ---------------------------------------------------------------------------
__global__ void ln_bf_kernel(const u16* __restrict__ in_bf,
                             const float* __restrict__ w, const float* __restrict__ b,
                             u16* __restrict__ out_bf, float* __restrict__ out_f)
{
    const int l = threadIdx.x & 63;
    const int row = blockIdx.x * 4 + (threadIdx.x >> 6);
    float v[8];
    ld8bf(in_bf + (size_t)row * EE + l * 8, v);
    float s = 0.f, s2 = 0.f;
    #pragma unroll
    for (int j = 0; j < 8; j++) { s += v[j]; s2 += v[j] * v[j]; }
    #pragma unroll
    for (int m = 1; m < 64; m <<= 1) { s += __shfl_xor(s, m); s2 += __shfl_xor(s2, m); }
    float mu  = s * (1.f / 512.f);
    float var = s2 * (1.f / 512.f) - mu * mu;
    float rs  = rsqrtf(var + 1e-5f);
    float4 w0 = *(const float4*)&w[l * 8], w1 = *(const float4*)&w[l * 8 + 4];
    float4 b0 = *(const float4*)&b[l * 8], b1 = *(const float4*)&b[l * 8 + 4];
    float o[8];
    o[0] = (v[0] - mu) * rs * w0.x + b0.x;
    o[1] = (v[1] - mu) * rs * w0.y + b0.y;
    o[2] = (v[2] - mu) * rs * w0.z + b0.z;
    o[3] = (v[3] - mu) * rs * w0.w + b0.w;
    o[4] = (v[4] - mu) * rs * w1.x + b1.x;
    o[5] = (v[5] - mu) * rs * w1.y + b1.y;
    o[6] = (v[6] - mu) * rs * w1.z + b1.z;
    o[7] = (v[7] - mu) * rs * w1.w + b1.w;
    if (out_bf) {
        uint4 pk;
        pk.x = (uint32_t)f2bf(o[0]) | ((uint32_t)f2bf(o[1]) << 16);
        pk.y = (uint32_t)f2bf(o[2]) | ((uint32_t)f2bf(o[3]) << 16);
        pk.z = (uint32_t)f2bf(o[4]) | ((uint32_t)f2bf(o[5]) << 16);
        pk.w = (uint32_t)f2bf(o[6]) | ((uint32_t)f2bf(o[7]) << 16);
        *(uint4*)(out_bf + (size_t)row * EE + l * 8) = pk;
    }
    if (out_f) {
        float* po = out_f + (size_t)row * EE + l * 8;
        *(float4*)po       = make_float4(o[0], o[1], o[2], o[3]);
        *(float4*)(po + 4) = make_float4(o[4], o[5], o[6], o[7]);
    }
}

// ---------------------------------------------------------------------------
extern "C" void kernel_launch(void* const* d_in, const int* in_sizes, int n_in,
                              void* d_out, int out_size, void* d_ws, size_t ws_size,
                              hipStream_t stream)
{
    const float* src        = (const float*)d_in[0];
    const float* conv_w     = (const float*)d_in[1];
    const float* conv_b     = (const float*)d_in[2];
    const float* in_proj_w  = (const float*)d_in[3];
    const float* in_proj_b  = (const float*)d_in[4];
    const float* out_proj_w = (const float*)d_in[5];
    const float* out_proj_b = (const float*)d_in[6];
    const float* ln1_w      = (const float*)d_in[7];
    const float* ln1_b      = (const float*)d_in[8];
    const float* ln2_w      = (const float*)d_in[9];
    const float* ln2_b      = (const float*)d_in[10];
    const float* w1         = (const float*)d_in[11];
    const float* b1         = (const float*)d_in[12];
    const float* w2         = (const float*)d_in[13];
    const float* b2         = (const float*)d_in[14];

    char*  wsb    = (char*)d_ws;
    float* out    = (float*)d_out;
    u16*   src_bf = (u16*)(wsb + B_SRCBF);
    u16*   lvl_bf = (u16*)(wsb + B_LVLBF);
    u16*   QKV    = (u16*)(wsb + B_QKV);
    u16*   KVs    = (u16*)(wsb + B_KVS);
    u16*   O_bf   = (u16*)(wsb + B_OBF);
    u16*   XPRE   = (u16*)(wsb + B_XPRE);
    u16*   OUTBF  = (u16*)(wsb + B_OUTBF);
    u16*   X_bf   = (u16*)(wsb + B_XBF);
    u16*   inw_bf = (u16*)(wsb + B_WBF);
    u16*   outw_bf= inw_bf + 786432;
    u16*   w1_bf  = outw_bf + 262144;
    u16*   w2_bf  = w1_bf + 1048576;
    u16*   cw_bf  = w2_bf + 1048576;
    u16*   FFH    = (u16*)(wsb + B_FFH);

    // 0) cast src + weights to bf16 (+ conv_w repack)
    cast_all_kernel<<<11344, 256, 0, stream>>>(src, in_proj_w, out_proj_w, w1, w2, conv_w,
                                               src_bf, inw_bf, outw_bf, w1_bf, w2_bf, cw_bf);

    // 1) conv chain (512 blocks) + QKV (768 blocks) in ONE dual launch
    conv_qkv_dual<<<512 + 768, 512, 0, stream>>>(
        src_bf, lvl_bf, cw_bf, conv_b, inw_bf, in_proj_b, QKV);

    // 2) conv tail (levels 9-10)
    conv_tail_kernel<<<NB * NHEADS, 256, 0, stream>>>(lvl_bf, cw_bf, conv_b);

    // 3) KVs = lvl_bf @ Wkv^T + b_kv  (16368 x 1024): v4, grid 64x8
    mfma_gemm<<<64 * 8, 512, 0, stream>>>(
        lvl_bf, inw_bf + (size_t)512 * 512, in_proj_b + 512, nullptr, KVs,
        16368, EE, 1024, 0, 8);

    // 4) attention -> O_bf  (XCD-chunked block swizzle)
    attn_kernel<<<BROWS / 4, 256, 0, stream>>>(QKV, KVs, O_bf);

    // 5) XPRE = out_proj (16384 x 512, K=512): v4, grid 256
    mfma_gemm<<<64 * 4, 512, 0, stream>>>(
        O_bf, outw_bf, out_proj_b, nullptr, XPRE, BROWS, EE, EE, 0, 4);

    // 6) LN1: X_bf = LN(XPRE)
    ln_bf_kernel<<<BROWS / 4, 256, 0, stream>>>(XPRE, ln1_w, ln1_b, X_bf, nullptr);

    // 7) FFN1 (16384 x 2048, K=512): v4, grid 64x16
    mfma_gemm<<<64 * 16, 512, 0, stream>>>(
        X_bf, w1_bf, b1, nullptr, FFH, BROWS, EE, DFF, 1, 16);

    // 8) FFN2 + residual (16384 x 512, K=2048): v4, grid 256
    mfma_gemm<<<64 * 4, 512, 0, stream>>>(
        FFH, w2_bf, b2, X_bf, OUTBF, BROWS, DFF, EE, 0, 4);

    // 9) LN2: out = LN(OUTBF)
    ln_bf_kernel<<<BROWS / 4, 256, 0, stream>>>(OUTBF, ln2_w, ln2_b, nullptr, out);
}

// Round 21
// 225.994 us; speedup vs baseline: 1.0087x; 1.0087x over previous
//
#include <hip/hip_runtime.h>
#include <hip/hip_bf16.h>
#include <stdint.h>
#include <math.h>

// Problem constants
#define NB      16
#define LL      1024
#define EE      512
#define NHEADS  8
#define DFF     2048
#define NLEVELS 10
#define NSCALES 11
#define BROWS   (NB * LL)       // 16384

typedef unsigned short u16;
typedef __attribute__((ext_vector_type(8))) short bf16x8;
typedef __attribute__((ext_vector_type(4))) float f32x4;

// ---------------- workspace layout (byte offsets) ----------------
static const size_t B_SRCBF = 0;
static const size_t B_LVLBF = 16777216;
static const size_t B_QKV   = 33538048;
static const size_t B_KVS   = 83869696;
static const size_t B_OBF   = 117391360;
static const size_t B_XPRE  = 134168576;
static const size_t B_OUTBF = 150945792;
static const size_t B_XBF   = 167723008;
static const size_t B_WBF   = 184500224;
static const size_t B_FFH   = 0;

// ---------------- helpers ----------------
__device__ __forceinline__ u16 f2bf(float x) {
    union { float f; uint32_t u; } c; c.f = x;
    uint32_t u = c.u + 0x7FFFu + ((c.u >> 16) & 1u);
    return (u16)(u >> 16);
}
__device__ __forceinline__ float bf2f(u16 v) {
    union { uint32_t u; float f; } c; c.u = ((uint32_t)v) << 16; return c.f;
}
__device__ __forceinline__ uint32_t addbf2(uint32_t a, uint32_t b) {
    float lo = bf2f((u16)(a & 0xFFFF)) + bf2f((u16)(b & 0xFFFF));
    float hi = bf2f((u16)(a >> 16))    + bf2f((u16)(b >> 16));
    return (uint32_t)f2bf(lo) | ((uint32_t)f2bf(hi) << 16);
}
__device__ __forceinline__ void ld8bf(const u16* p, float* f) {
    uint4 r = *(const uint4*)p;
    uint32_t ws[4] = { r.x, r.y, r.z, r.w };
    #pragma unroll
    for (int j = 0; j < 4; j++) {
        union { uint32_t u; float g; } lo, hi;
        lo.u = ws[j] << 16; hi.u = ws[j] & 0xFFFF0000u;
        f[2 * j] = lo.g; f[2 * j + 1] = hi.g;
    }
}
__device__ __forceinline__ void gload16(const u16* g, u16* l) {
    __builtin_amdgcn_global_load_lds(
        (const __attribute__((address_space(1))) void*)g,
        (__attribute__((address_space(3))) void*)l, 16, 0, 0);
}

// ---------------------------------------------------------------------------
// Fused cast kernel.
// ---------------------------------------------------------------------------
__global__ void cast_all_kernel(const float* __restrict__ s0, const float* __restrict__ s1,
                                const float* __restrict__ s2, const float* __restrict__ s3,
                                const float* __restrict__ s4, const float* __restrict__ cw,
                                u16* __restrict__ d0, u16* __restrict__ d1,
                                u16* __restrict__ d2, u16* __restrict__ d3,
                                u16* __restrict__ d4, u16* __restrict__ dw)
{
    int bid = blockIdx.x;
    if (bid >= 11264) {
        int base = (bid - 11264) * 1024 + threadIdx.x * 4;
        #pragma unroll
        for (int j = 0; j < 4; j++) {
            int idx = base + j;
            int lvl = idx >> 13, rem = idx & 8191;
            int o = rem >> 7, ck = rem & 127;
            int k = ck >> 6, ci = ck & 63;
            dw[idx] = f2bf(cw[(lvl << 13) + (o << 7) + (ci << 1) + k]);
        }
        return;
    }
    const float* s; u16* d; int nt;
    if      (bid < 8192)  { s = s0; d = d0; nt = 2097152; }
    else if (bid < 8960)  { bid -= 8192;  s = s1; d = d1; nt = 196608; }
    else if (bid < 9216)  { bid -= 8960;  s = s2; d = d2; nt = 65536;  }
    else if (bid < 10240) { bid -= 9216;  s = s3; d = d3; nt = 262144; }
    else                  { bid -= 10240; s = s4; d = d4; nt = 262144; }
    int i = bid * 256 + threadIdx.x;
    if (i < nt) {
        float4 v = ((const float4*)s)[i];
        uint2 o;
        o.x = (uint32_t)f2bf(v.x) | ((uint32_t)f2bf(v.y) << 16);
        o.y = (uint32_t)f2bf(v.z) | ((uint32_t)f2bf(v.w) << 16);
        ((uint2*)d)[i] = o;
    }
}

// ---------------------------------------------------------------------------
// Conv chain kernel: levels 1..8 in ONE launch (256 threads, r13-proven).
// ---------------------------------------------------------------------------
__global__ __launch_bounds__(256, 2)
void conv_chain_kernel(const u16* __restrict__ src_bf, u16* __restrict__ lvl_bf,
                       const u16* __restrict__ cw, const float* __restrict__ cb)
{
    __shared__ u16 BIG[16384];
    __shared__ u16 MID[8192];
    __shared__ u16 WB[8192];
    const int tid = threadIdx.x;
    const int l = tid & 63, w = tid >> 6;
    const int bid = blockIdx.x;
    const int q  = bid & 3;
    const int h  = (bid >> 2) & 7;
    const int n  = bid >> 5;

    {
        const u16* base = src_bf + ((size_t)n * 1024 + q * 256) * 512 + h * 64;
        #pragma unroll
        for (int j = 0; j < 8; j++) {
            int c = j * 256 + w * 64 + l;
            int row = c >> 3, lch = c & 7;
            int gch = lch ^ (row & 7);
            gload16(base + (size_t)row * 512 + gch * 8,
                    BIG + (size_t)(j * 256 + w * 64) * 8);
        }
    }

    const u16* IN = BIG;
    u16* OUTb = MID;
    int R = 128;
    int T = 512;
    size_t rowOff = 0;
    for (int lvl = 1; lvl <= 8; lvl++) {
        {
            const u16* wsrc = cw + (size_t)(lvl - 1) * 8192;
            #pragma unroll
            for (int j = 0; j < 4; j++) {
                int c = j * 256 + w * 64 + l;
                int o = c >> 4, lch = c & 15;
                int gch = lch ^ (o & 7);
                gload16(wsrc + o * 128 + gch * 8, WB + (size_t)(j * 256 + w * 64) * 8);
            }
        }
        asm volatile("s_waitcnt vmcnt(0)" ::: "memory");
        __syncthreads();

        const int nrt = (R + 15) >> 4;
        const int maxil = 2 * R - 1;
        for (int f = w; f < nrt * 4; f += 4) {
            int rt = f >> 2, nc = f & 3;
            int o = nc * 16 + (l & 15);
            f32x4 acc = {0.f, 0.f, 0.f, 0.f};
            #pragma unroll
            for (int s = 0; s < 4; s++) {
                int il = 2 * (rt * 16 + (l & 15)) + (s >> 1);
                if (il > maxil) il = maxil;
                int ach = (((s & 1) * 4) + (l >> 4)) ^ (il & 7);
                bf16x8 av = *(const bf16x8*)(IN + il * 64 + ach * 8);
                int bch = (s * 4 + (l >> 4)) ^ (o & 7);
                bf16x8 bv = *(const bf16x8*)(WB + o * 128 + bch * 8);
                acc = __builtin_amdgcn_mfma_f32_16x16x32_bf16(av, bv, acc, 0, 0, 0);
            }
            float bb = cb[(lvl - 1) * 64 + o];
            #pragma unroll
            for (int reg = 0; reg < 4; reg++) {
                int rloc = rt * 16 + (l >> 4) * 4 + reg;
                if (rloc < R) {
                    float v = fmaxf(acc[reg] + bb, 0.f);
                    u16 b16 = f2bf(v);
                    lvl_bf[(rowOff + (size_t)n * T + (size_t)q * R + rloc) * 512 + h * 64 + o] = b16;
                    OUTb[rloc * 64 + (((o >> 3) ^ (rloc & 7)) << 3) + (o & 7)] = b16;
                }
            }
        }
        __syncthreads();
        const u16* tmp = IN; IN = OUTb; OUTb = (u16*)tmp;
        rowOff += (size_t)16 * T;
        T >>= 1; R >>= 1;
    }
}

// ---------------------------------------------------------------------------
// Conv tail (levels 9-10).
// ---------------------------------------------------------------------------
__global__ void conv_tail_kernel(u16* __restrict__ lvl_bf, const u16* __restrict__ cw,
                                 const float* __restrict__ cb)
{
    const int h = blockIdx.x & 7, n = blockIdx.x >> 3;
    const int tid = threadIdx.x;
    __shared__ float L8s[4][64];
    __shared__ float L9s[2][64];
    {
        int r = tid >> 6, c = tid & 63;
        L8s[r][c] = bf2f(lvl_bf[((size_t)16256 + n * 4 + r) * 512 + h * 64 + c]);
    }
    __syncthreads();
    if (tid < 128) {
        int t = tid >> 6, o = tid & 63;
        const u16* wr = cw + (size_t)8 * 8192 + o * 128;
        float acc = cb[8 * 64 + o];
        #pragma unroll
        for (int k = 0; k < 2; k++)
            #pragma unroll 16
            for (int ci = 0; ci < 64; ci++)
                acc += L8s[2 * t + k][ci] * bf2f(wr[k * 64 + ci]);
        acc = fmaxf(acc, 0.f);
        L9s[t][o] = acc;
        lvl_bf[((size_t)16320 + n * 2 + t) * 512 + h * 64 + o] = f2bf(acc);
    }
    __syncthreads();
    if (tid < 64) {
        int o = tid;
        const u16* wr = cw + (size_t)9 * 8192 + o * 128;
        float acc = cb[9 * 64 + o];
        #pragma unroll
        for (int k = 0; k < 2; k++)
            #pragma unroll 16
            for (int ci = 0; ci < 64; ci++)
                acc += L9s[k][ci] * bf2f(wr[k * 64 + ci]);
        acc = fmaxf(acc, 0.f);
        lvl_bf[((size_t)16352 + n) * 512 + h * 64 + o] = f2bf(acc);
    }
}

// ---------------------------------------------------------------------------
// v4 GEMM body (round-13 proven).
// ---------------------------------------------------------------------------
__device__ __forceinline__ void gemm_v4_body(
    u16* lds,
    const u16* __restrict__ A, const u16* __restrict__ W,
    const float* __restrict__ bias, const u16* __restrict__ resb,
    u16* __restrict__ Cb, int M, int K, int N, int relu, int gx,
    int nwg, int bid)
{
    const int tid = threadIdx.x;
    const int l = tid & 63, w = tid >> 6;
    const int wm = w >> 1, wn = w & 1;

    const int q = nwg >> 3, r = nwg & 7;
    const int xcd = bid & 7, idx = bid >> 3;
    const int lin = (xcd < r ? xcd * (q + 1) : r * (q + 1) + (xcd - r) * q) + idx;
    const int by = lin / gx, bx = lin - by * gx;
    const int rowBase = by * 256, colBase = bx * 128;

    f32x4 acc[4][4];
    #pragma unroll
    for (int m = 0; m < 4; m++)
        #pragma unroll
        for (int n = 0; n < 4; n++) acc[m][n] = 0.f;

    const u16* gApt[2];
    const u16* gBpt;
    #pragma unroll
    for (int i = 0; i < 2; i++) {
        int G = i * 512 + tid;
        int row = G >> 2, p = G & 3;
        int c = p ^ ((row >> 1) & 3);
        int grow = rowBase + row; if (grow > M - 1) grow = M - 1;
        gApt[i] = A + (size_t)grow * K + c * 8;
    }
    {
        int G = tid;
        int row = G >> 2, p = G & 3;
        int c = p ^ ((row >> 1) & 3);
        gBpt = W + (size_t)(colBase + row) * K + c * 8;
    }

    const int NT = K >> 5;
    auto STAGE = [&](int tt, int buf) {
        const int kb = tt << 5;
        u16* dA = lds + buf * 12288;
        u16* dB = dA + 8192;
        gload16(gApt[0] + kb, dA + (size_t)(w * 64) * 8);
        gload16(gApt[1] + kb, dA + (size_t)(512 + w * 64) * 8);
        gload16(gBpt + kb, dB + (size_t)(w * 64) * 8);
    };
    STAGE(0, 0);
    if (NT > 1) STAGE(1, 1);

    int cbuf = 0, sbuf = 2;
    for (int t = 0; t < NT; ++t) {
        if (t + 1 < NT) asm volatile("s_waitcnt vmcnt(3)" ::: "memory");
        else            asm volatile("s_waitcnt vmcnt(0)" ::: "memory");
        __builtin_amdgcn_s_barrier();
        __builtin_amdgcn_sched_barrier(0);
        if (t + 2 < NT) STAGE(t + 2, sbuf);

        const u16* Ab = lds + cbuf * 12288;
        const u16* Bb = Ab + 8192;
        const int c = l >> 4;
        bf16x8 av[4], bv[4];
        #pragma unroll
        for (int fr = 0; fr < 4; fr++) {
            int row = wm * 64 + fr * 16 + (l & 15);
            av[fr] = *(const bf16x8*)(Ab + row * 32 + ((c ^ ((row >> 1) & 3)) * 8));
        }
        #pragma unroll
        for (int fc = 0; fc < 4; fc++) {
            int col = wn * 64 + fc * 16 + (l & 15);
            bv[fc] = *(const bf16x8*)(Bb + col * 32 + ((c ^ ((col >> 1) & 3)) * 8));
        }
        __builtin_amdgcn_s_setprio(1);
        #pragma unroll
        for (int m = 0; m < 4; m++)
            #pragma unroll
            for (int n = 0; n < 4; n++)
                acc[m][n] = __builtin_amdgcn_mfma_f32_16x16x32_bf16(av[m], bv[n], acc[m][n], 0, 0, 0);
        __builtin_amdgcn_s_setprio(0);

        cbuf = (cbuf == 2) ? 0 : cbuf + 1;
        sbuf = (sbuf == 2) ? 0 : sbuf + 1;
    }
    __builtin_amdgcn_s_barrier();
    __builtin_amdgcn_sched_barrier(0);

    const int cc = colBase + wn * 64 + (l & 15);
    float bs4[4];
    #pragma unroll
    for (int n = 0; n < 4; n++) bs4[n] = bias[cc + n * 16];

    u16* WS = lds + w * 2048;
    #pragma unroll
    for (int hh = 0; hh < 2; hh++) {
        #pragma unroll
        for (int mi = 0; mi < 2; mi++) {
            #pragma unroll
            for (int n = 0; n < 4; n++) {
                int colv = n * 16 + (l & 15);
                #pragma unroll
                for (int reg = 0; reg < 4; reg++) {
                    int rowh = mi * 16 + (l >> 4) * 4 + reg;
                    float v = acc[hh * 2 + mi][n][reg] + bs4[n];
                    if (relu) v = fmaxf(v, 0.f);
                    WS[rowh * 64 + (colv ^ (((rowh >> 2) & 3) << 4))] = f2bf(v);
                }
            }
        }
        asm volatile("s_waitcnt lgkmcnt(0)" ::: "memory");
        __builtin_amdgcn_sched_barrier(0);
        #pragma unroll
        for (int j = 0; j < 4; j++) {
            int rowh = (l >> 3) + 8 * j;
            int col8 = (l & 7) * 8;
            int colx = col8 ^ (((rowh >> 2) & 3) << 4);
            uint4 v = *(const uint4*)(WS + rowh * 64 + colx);
            int grow = rowBase + wm * 64 + hh * 32 + rowh;
            if (grow < M) {
                int gcol = colBase + wn * 64 + col8;
                if (resb) {
                    uint4 rb = *(const uint4*)&resb[(size_t)grow * N + gcol];
                    v.x = addbf2(v.x, rb.x);
                    v.y = addbf2(v.y, rb.y);
                    v.z = addbf2(v.z, rb.z);
                    v.w = addbf2(v.w, rb.w);
                }
                *(uint4*)(Cb + (size_t)grow * N + gcol) = v;
            }
        }
        asm volatile("s_waitcnt lgkmcnt(0)" ::: "memory");
    }
}

__global__ __launch_bounds__(512, 4)
void mfma_gemm(const u16* __restrict__ A, const u16* __restrict__ W,
               const float* __restrict__ bias, const u16* __restrict__ resb,
               u16* __restrict__ Cb, int M, int K, int N, int relu, int gx)
{
    __shared__ u16 lds[36864];
    gemm_v4_body(lds, A, W, bias, resb, Cb, M, K, N, relu, gx,
                 gridDim.x, blockIdx.x);
}

// Dual-problem launch: blocks [0,n0) -> problem 0, [n0,n0+n1) -> problem 1.
__global__ __launch_bounds__(512, 4)
void mfma_gemm_dual(const u16* __restrict__ A0, const u16* __restrict__ W0,
                    const float* __restrict__ b0, u16* __restrict__ C0,
                    int M0, int K0, int N0, int gx0, int n0,
                    const u16* __restrict__ A1, const u16* __restrict__ W1,
                    const float* __restrict__ b1, u16* __restrict__ C1,
                    int M1, int K1, int N1, int gx1, int n1)
{
    __shared__ u16 lds[36864];
    if ((int)blockIdx.x < n0)
        gemm_v4_body(lds, A0, W0, b0, nullptr, C0, M0, K0, N0, 0, gx0,
                     n0, blockIdx.x);
    else
        gemm_v4_body(lds, A1, W1, b1, nullptr, C1, M1, K1, N1, 0, gx1,
                     n1, blockIdx.x - n0);
}

// ---------------------------------------------------------------------------
// Attention (bf16 in/out) with XCD-chunked block swizzle.
// ---------------------------------------------------------------------------
__global__ void attn_kernel(const u16* __restrict__ QKV, const u16* __restrict__ KVs,
                            u16* __restrict__ O)
{
    const int wv   = threadIdx.x >> 6;
    const int lane = threadIdx.x & 63;
    const int bswz = (blockIdx.x & 7) * (gridDim.x >> 3) + (blockIdx.x >> 3);
    const int b    = bswz * 4 + wv;
    const int h    = lane >> 3;
    const int d8   = lane & 7;
    const int n = b >> 10, pos = b & 1023;

    float q[8];
    ld8bf(QKV + (size_t)b * 1536 + h * 64 + d8 * 8, q);

    float sc[NSCALES];
    {
        float kk[8];
        ld8bf(QKV + (size_t)b * 1536 + 512 + h * 64 + d8 * 8, kk);
        float p = 0.f;
        #pragma unroll
        for (int j = 0; j < 8; j++) p += q[j] * kk[j];
        p += __shfl_xor(p, 1); p += __shfl_xor(p, 2); p += __shfl_xor(p, 4);
        sc[0] = p * 0.125f;
    }
    {
        int rowOff = 0;
        #pragma unroll
        for (int s = 1; s <= NLEVELS; s++) {
            int Ls = 1024 >> s;
            int row = rowOff + n * Ls + (pos >> s);
            float kk[8];
            ld8bf(KVs + (size_t)row * 1024 + h * 64 + d8 * 8, kk);
            float p = 0.f;
            #pragma unroll
            for (int j = 0; j < 8; j++) p += q[j] * kk[j];
            p += __shfl_xor(p, 1); p += __shfl_xor(p, 2); p += __shfl_xor(p, 4);
            sc[s] = p * 0.125f;
            rowOff += 16 * Ls;
        }
    }
    float m = sc[0];
    #pragma unroll
    for (int s = 1; s < NSCALES; s++) m = fmaxf(m, sc[s]);
    float sum = 0.f;
    #pragma unroll
    for (int s = 0; s < NSCALES; s++) { sc[s] = __expf(sc[s] - m); sum += sc[s]; }
    float inv = 1.f / sum;

    float o[8] = {};
    {
        float vv[8];
        ld8bf(QKV + (size_t)b * 1536 + 1024 + h * 64 + d8 * 8, vv);
        float a = sc[0] * inv;
        #pragma unroll
        for (int j = 0; j < 8; j++) o[j] += a * vv[j];
    }
    {
        int rowOff = 0;
        #pragma unroll
        for (int s = 1; s <= NLEVELS; s++) {
            int Ls = 1024 >> s;
            int row = rowOff + n * Ls + (pos >> s);
            float vv[8];
            ld8bf(KVs + (size_t)row * 1024 + 512 + h * 64 + d8 * 8, vv);
            float a = sc[s] * inv;
            #pragma unroll
            for (int j = 0; j < 8; j++) o[j] += a * vv[j];
            rowOff += 16 * Ls;
        }
    }
    uint4 pk;
    pk.x = (uint32_t)f2bf(o[0]) | ((uint32_t)f2bf(o[1]) << 16);
    pk.y = (uint32_t)f2bf(o[2]) | ((uint32_t)f2bf(o[3]) << 16);
    pk.z = (uint32_t)f2bf(o[4]) | ((uint32_t)f2bf(o[5]) << 16);
    pk.w = (uint32_t)f2bf(o[6]) | ((uint32_t)f2bf(o[7]) << 16);
    *(uint4*)(O + (size_t)b * 512 + h * 64 + d8 * 8) = pk;
}

// ---------------------------------------------------------------------------
// LayerNorm over E=512, bf16 input.
// ---------------------------------------------------------------------------
__global__ void ln_bf_kernel(const u16* __restrict__ in_bf,
                             const float* __restrict__ w, const float* __restrict__ b,
                             u16* __restrict__ out_bf, float* __restrict__ out_f)
{
    const int l = threadIdx.x & 63;
    const int row = blockIdx.x * 4 + (threadIdx.x >> 6);
    float v[8];
    ld8bf(in_bf + (size_t)row * EE + l * 8, v);
    float s = 0.f, s2 = 0.f;
    #pragma unroll
    for (int j = 0; j < 8; j++) { s += v[j]; s2 += v[j] * v[j]; }
    #pragma unroll
    for (int m = 1; m < 64; m <<= 1) { s += __shfl_xor(s, m); s2 += __shfl_xor(s2, m); }
    float mu  = s * (1.f / 512.f);
    float var = s2 * (1.f / 512.f) - mu * mu;
    float rs  = rsqrtf(var + 1e-5f);
    float4 w0 = *(const float4*)&w[l * 8], w1 = *(const float4*)&w[l * 8 + 4];
    float4 b0 = *(const float4*)&b[l * 8], b1 = *(const float4*)&b[l * 8 + 4];
    float o[8];
    o[0] = (v[0] - mu) * rs * w0.x + b0.x;
    o[1] = (v[1] - mu) * rs * w0.y + b0.y;
    o[2] = (v[2] - mu) * rs * w0.z + b0.z;
    o[3] = (v[3] - mu) * rs * w0.w + b0.w;
    o[4] = (v[4] - mu) * rs * w1.x + b1.x;
    o[5] = (v[5] - mu) * rs * w1.y + b1.y;
    o[6] = (v[6] - mu) * rs * w1.z + b1.z;
    o[7] = (v[7] - mu) * rs * w1.w + b1.w;
    if (out_bf) {
        uint4 pk;
        pk.x = (uint32_t)f2bf(o[0]) | ((uint32_t)f2bf(o[1]) << 16);
        pk.y = (uint32_t)f2bf(o[2]) | ((uint32_t)f2bf(o[3]) << 16);
        pk.z = (uint32_t)f2bf(o[4]) | ((uint32_t)f2bf(o[5]) << 16);
        pk.w = (uint32_t)f2bf(o[6]) | ((uint32_t)f2bf(o[7]) << 16);
        *(uint4*)(out_bf + (size_t)row * EE + l * 8) = pk;
    }
    if (out_f) {
        float* po = out_f + (size_t)row * EE + l * 8;
        *(float4*)po       = make_float4(o[0], o[1], o[2], o[3]);
        *(float4*)(po + 4) = make_float4(o[4], o[5], o[6], o[7]);
    }
}

// ---------------------------------------------------------------------------
extern "C" void kernel_launch(void* const* d_in, const int* in_sizes, int n_in,
                              void* d_out, int out_size, void* d_ws, size_t ws_size,
                              hipStream_t stream)
{
    const float* src        = (const float*)d_in[0];
    const float* conv_w     = (const float*)d_in[1];
    const float* conv_b     = (const float*)d_in[2];
    const float* in_proj_w  = (const float*)d_in[3];
    const float* in_proj_b  = (const float*)d_in[4];
    const float* out_proj_w = (const float*)d_in[5];
    const float* out_proj_b = (const float*)d_in[6];
    const float* ln1_w      = (const float*)d_in[7];
    const float* ln1_b      = (const float*)d_in[8];
    const float* ln2_w      = (const float*)d_in[9];
    const float* ln2_b      = (const float*)d_in[10];
    const float* w1         = (const float*)d_in[11];
    const float* b1         = (const float*)d_in[12];
    const float* w2         = (const float*)d_in[13];
    const float* b2         = (const float*)d_in[14];

    char*  wsb    = (char*)d_ws;
    float* out    = (float*)d_out;
    u16*   src_bf = (u16*)(wsb + B_SRCBF);
    u16*   lvl_bf = (u16*)(wsb + B_LVLBF);
    u16*   QKV    = (u16*)(wsb + B_QKV);
    u16*   KVs    = (u16*)(wsb + B_KVS);
    u16*   O_bf   = (u16*)(wsb + B_OBF);
    u16*   XPRE   = (u16*)(wsb + B_XPRE);
    u16*   OUTBF  = (u16*)(wsb + B_OUTBF);
    u16*   X_bf   = (u16*)(wsb + B_XBF);
    u16*   inw_bf = (u16*)(wsb + B_WBF);
    u16*   outw_bf= inw_bf + 786432;
    u16*   w1_bf  = outw_bf + 262144;
    u16*   w2_bf  = w1_bf + 1048576;
    u16*   cw_bf  = w2_bf + 1048576;
    u16*   FFH    = (u16*)(wsb + B_FFH);

    // 0) cast src + weights to bf16 (+ conv_w repack)
    cast_all_kernel<<<11344, 256, 0, stream>>>(src, in_proj_w, out_proj_w, w1, w2, conv_w,
                                               src_bf, inw_bf, outw_bf, w1_bf, w2_bf, cw_bf);

    // 1) conv pyramid
    conv_chain_kernel<<<NB * NHEADS * 4, 256, 0, stream>>>(src_bf, lvl_bf, cw_bf, conv_b);
    conv_tail_kernel<<<NB * NHEADS, 256, 0, stream>>>(lvl_bf, cw_bf, conv_b);

    // 2+3) QKV (16384x1536) and KVs (16368x1024) as ONE dual launch:
    //      blocks [0,768) -> QKV, [768,1280) -> KVs (tail backfill).
    mfma_gemm_dual<<<768 + 512, 512, 0, stream>>>(
        src_bf, inw_bf, in_proj_b, QKV, BROWS, EE, 1536, 12, 768,
        lvl_bf, inw_bf + (size_t)512 * 512, in_proj_b + 512, KVs,
        16368, EE, 1024, 8, 512);

    // 4) attention -> O_bf  (XCD-chunked block swizzle)
    attn_kernel<<<BROWS / 4, 256, 0, stream>>>(QKV, KVs, O_bf);

    // 5) XPRE = out_proj (16384 x 512, K=512): v4, grid 256
    mfma_gemm<<<64 * 4, 512, 0, stream>>>(
        O_bf, outw_bf, out_proj_b, nullptr, XPRE, BROWS, EE, EE, 0, 4);

    // 6) LN1: X_bf = LN(XPRE)
    ln_bf_kernel<<<BROWS / 4, 256, 0, stream>>>(XPRE, ln1_w, ln1_b, X_bf, nullptr);

    // 7) FFN1 (16384 x 2048, K=512): v4, grid 64x16
    mfma_gemm<<<64 * 16, 512, 0, stream>>>(
        X_bf, w1_bf, b1, nullptr, FFH, BROWS, EE, DFF, 1, 16);

    // 8) FFN2 + residual (16384 x 512, K=2048): v4, grid 256
    mfma_gemm<<<64 * 4, 512, 0, stream>>>(
        FFH, w2_bf, b2, X_bf, OUTBF, BROWS, DFF, EE, 0, 4);

    // 9) LN2: out = LN(OUTBF)
    ln_bf_kernel<<<BROWS / 4, 256, 0, stream>>>(OUTBF, ln2_w, ln2_b, nullptr, out);
}

// Round 22
// 224.767 us; speedup vs baseline: 1.0142x; 1.0055x over previous
//
#include <hip/hip_runtime.h>
#include <hip/hip_bf16.h>
#include <stdint.h>
#include <math.h>

// Problem constants
#define NB      16
#define LL      1024
#define EE      512
#define NHEADS  8
#define DFF     2048
#define NLEVELS 10
#define NSCALES 11
#define BROWS   (NB * LL)       // 16384

typedef unsigned short u16;
typedef __attribute__((ext_vector_type(8))) short bf16x8;
typedef __attribute__((ext_vector_type(4))) float f32x4;

// ---------------- workspace layout (byte offsets) ----------------
static const size_t B_SRCBF = 0;
static const size_t B_LVLBF = 16777216;
static const size_t B_QKV   = 33538048;
static const size_t B_KVS   = 83869696;
static const size_t B_OBF   = 117391360;
static const size_t B_XPRE  = 134168576;
static const size_t B_OUTBF = 150945792;
static const size_t B_XBF   = 167723008;
static const size_t B_WBF   = 184500224;
static const size_t B_FFH   = 0;

// ---------------- helpers ----------------
__device__ __forceinline__ u16 f2bf(float x) {
    union { float f; uint32_t u; } c; c.f = x;
    uint32_t u = c.u + 0x7FFFu + ((c.u >> 16) & 1u);
    return (u16)(u >> 16);
}
__device__ __forceinline__ float bf2f(u16 v) {
    union { uint32_t u; float f; } c; c.u = ((uint32_t)v) << 16; return c.f;
}
__device__ __forceinline__ uint32_t addbf2(uint32_t a, uint32_t b) {
    float lo = bf2f((u16)(a & 0xFFFF)) + bf2f((u16)(b & 0xFFFF));
    float hi = bf2f((u16)(a >> 16))    + bf2f((u16)(b >> 16));
    return (uint32_t)f2bf(lo) | ((uint32_t)f2bf(hi) << 16);
}
__device__ __forceinline__ void ld8bf(const u16* p, float* f) {
    uint4 r = *(const uint4*)p;
    uint32_t ws[4] = { r.x, r.y, r.z, r.w };
    #pragma unroll
    for (int j = 0; j < 4; j++) {
        union { uint32_t u; float g; } lo, hi;
        lo.u = ws[j] << 16; hi.u = ws[j] & 0xFFFF0000u;
        f[2 * j] = lo.g; f[2 * j + 1] = hi.g;
    }
}
__device__ __forceinline__ void gload16(const u16* g, u16* l) {
    __builtin_amdgcn_global_load_lds(
        (const __attribute__((address_space(1))) void*)g,
        (__attribute__((address_space(3))) void*)l, 16, 0, 0);
}

// ---------------------------------------------------------------------------
// Fused cast kernel.
// ---------------------------------------------------------------------------
__global__ void cast_all_kernel(const float* __restrict__ s0, const float* __restrict__ s1,
                                const float* __restrict__ s2, const float* __restrict__ s3,
                                const float* __restrict__ s4, const float* __restrict__ cw,
                                u16* __restrict__ d0, u16* __restrict__ d1,
                                u16* __restrict__ d2, u16* __restrict__ d3,
                                u16* __restrict__ d4, u16* __restrict__ dw)
{
    int bid = blockIdx.x;
    if (bid >= 11264) {
        int base = (bid - 11264) * 1024 + threadIdx.x * 4;
        #pragma unroll
        for (int j = 0; j < 4; j++) {
            int idx = base + j;
            int lvl = idx >> 13, rem = idx & 8191;
            int o = rem >> 7, ck = rem & 127;
            int k = ck >> 6, ci = ck & 63;
            dw[idx] = f2bf(cw[(lvl << 13) + (o << 7) + (ci << 1) + k]);
        }
        return;
    }
    const float* s; u16* d; int nt;
    if      (bid < 8192)  { s = s0; d = d0; nt = 2097152; }
    else if (bid < 8960)  { bid -= 8192;  s = s1; d = d1; nt = 196608; }
    else if (bid < 9216)  { bid -= 8960;  s = s2; d = d2; nt = 65536;  }
    else if (bid < 10240) { bid -= 9216;  s = s3; d = d3; nt = 262144; }
    else                  { bid -= 10240; s = s4; d = d4; nt = 262144; }
    int i = bid * 256 + threadIdx.x;
    if (i < nt) {
        float4 v = ((const float4*)s)[i];
        uint2 o;
        o.x = (uint32_t)f2bf(v.x) | ((uint32_t)f2bf(v.y) << 16);
        o.y = (uint32_t)f2bf(v.z) | ((uint32_t)f2bf(v.w) << 16);
        ((uint2*)d)[i] = o;
    }
}

// ---------------------------------------------------------------------------
// Conv chain kernel: levels 1..8 in ONE launch (256 threads, r13-proven).
// ---------------------------------------------------------------------------
__global__ __launch_bounds__(256, 2)
void conv_chain_kernel(const u16* __restrict__ src_bf, u16* __restrict__ lvl_bf,
                       const u16* __restrict__ cw, const float* __restrict__ cb)
{
    __shared__ u16 BIG[16384];
    __shared__ u16 MID[8192];
    __shared__ u16 WB[8192];
    const int tid = threadIdx.x;
    const int l = tid & 63, w = tid >> 6;
    const int bid = blockIdx.x;
    const int q  = bid & 3;
    const int h  = (bid >> 2) & 7;
    const int n  = bid >> 5;

    {
        const u16* base = src_bf + ((size_t)n * 1024 + q * 256) * 512 + h * 64;
        #pragma unroll
        for (int j = 0; j < 8; j++) {
            int c = j * 256 + w * 64 + l;
            int row = c >> 3, lch = c & 7;
            int gch = lch ^ (row & 7);
            gload16(base + (size_t)row * 512 + gch * 8,
                    BIG + (size_t)(j * 256 + w * 64) * 8);
        }
    }

    const u16* IN = BIG;
    u16* OUTb = MID;
    int R = 128;
    int T = 512;
    size_t rowOff = 0;
    for (int lvl = 1; lvl <= 8; lvl++) {
        {
            const u16* wsrc = cw + (size_t)(lvl - 1) * 8192;
            #pragma unroll
            for (int j = 0; j < 4; j++) {
                int c = j * 256 + w * 64 + l;
                int o = c >> 4, lch = c & 15;
                int gch = lch ^ (o & 7);
                gload16(wsrc + o * 128 + gch * 8, WB + (size_t)(j * 256 + w * 64) * 8);
            }
        }
        asm volatile("s_waitcnt vmcnt(0)" ::: "memory");
        __syncthreads();

        const int nrt = (R + 15) >> 4;
        const int maxil = 2 * R - 1;
        for (int f = w; f < nrt * 4; f += 4) {
            int rt = f >> 2, nc = f & 3;
            int o = nc * 16 + (l & 15);
            f32x4 acc = {0.f, 0.f, 0.f, 0.f};
            #pragma unroll
            for (int s = 0; s < 4; s++) {
                int il = 2 * (rt * 16 + (l & 15)) + (s >> 1);
                if (il > maxil) il = maxil;
                int ach = (((s & 1) * 4) + (l >> 4)) ^ (il & 7);
                bf16x8 av = *(const bf16x8*)(IN + il * 64 + ach * 8);
                int bch = (s * 4 + (l >> 4)) ^ (o & 7);
                bf16x8 bv = *(const bf16x8*)(WB + o * 128 + bch * 8);
                acc = __builtin_amdgcn_mfma_f32_16x16x32_bf16(av, bv, acc, 0, 0, 0);
            }
            float bb = cb[(lvl - 1) * 64 + o];
            #pragma unroll
            for (int reg = 0; reg < 4; reg++) {
                int rloc = rt * 16 + (l >> 4) * 4 + reg;
                if (rloc < R) {
                    float v = fmaxf(acc[reg] + bb, 0.f);
                    u16 b16 = f2bf(v);
                    lvl_bf[(rowOff + (size_t)n * T + (size_t)q * R + rloc) * 512 + h * 64 + o] = b16;
                    OUTb[rloc * 64 + (((o >> 3) ^ (rloc & 7)) << 3) + (o & 7)] = b16;
                }
            }
        }
        __syncthreads();
        const u16* tmp = IN; IN = OUTb; OUTb = (u16*)tmp;
        rowOff += (size_t)16 * T;
        T >>= 1; R >>= 1;
    }
}

// ---------------------------------------------------------------------------
// Conv tail (levels 9-10).
// ---------------------------------------------------------------------------
__global__ void conv_tail_kernel(u16* __restrict__ lvl_bf, const u16* __restrict__ cw,
                                 const float* __restrict__ cb)
{
    const int h = blockIdx.x & 7, n = blockIdx.x >> 3;
    const int tid = threadIdx.x;
    __shared__ float L8s[4][64];
    __shared__ float L9s[2][64];
    {
        int r = tid >> 6, c = tid & 63;
        L8s[r][c] = bf2f(lvl_bf[((size_t)16256 + n * 4 + r) * 512 + h * 64 + c]);
    }
    __syncthreads();
    if (tid < 128) {
        int t = tid >> 6, o = tid & 63;
        const u16* wr = cw + (size_t)8 * 8192 + o * 128;
        float acc = cb[8 * 64 + o];
        #pragma unroll
        for (int k = 0; k < 2; k++)
            #pragma unroll 16
            for (int ci = 0; ci < 64; ci++)
                acc += L8s[2 * t + k][ci] * bf2f(wr[k * 64 + ci]);
        acc = fmaxf(acc, 0.f);
        L9s[t][o] = acc;
        lvl_bf[((size_t)16320 + n * 2 + t) * 512 + h * 64 + o] = f2bf(acc);
    }
    __syncthreads();
    if (tid < 64) {
        int o = tid;
        const u16* wr = cw + (size_t)9 * 8192 + o * 128;
        float acc = cb[9 * 64 + o];
        #pragma unroll
        for (int k = 0; k < 2; k++)
            #pragma unroll 16
            for (int ci = 0; ci < 64; ci++)
                acc += L9s[k][ci] * bf2f(wr[k * 64 + ci]);
        acc = fmaxf(acc, 0.f);
        lvl_bf[((size_t)16352 + n) * 512 + h * 64 + o] = f2bf(acc);
    }
}

// ---------------------------------------------------------------------------
// v4 GEMM body (round-13 proven): 256x128, BK=32, 8 waves, 3-ring 72KB,
// single barrier/iter, involution swizzle p=c^((row>>1)&3), setprio,
// bf16 output, optional bf16 residual added in the coalesced store phase.
// ---------------------------------------------------------------------------
__device__ __forceinline__ void gemm_v4_body(
    u16* lds,
    const u16* __restrict__ A, const u16* __restrict__ W,
    const float* __restrict__ bias, const u16* __restrict__ resb,
    u16* __restrict__ Cb, int M, int K, int N, int relu, int gx,
    int nwg, int bid)
{
    const int tid = threadIdx.x;
    const int l = tid & 63, w = tid >> 6;
    const int wm = w >> 1, wn = w & 1;

    const int q = nwg >> 3, r = nwg & 7;
    const int xcd = bid & 7, idx = bid >> 3;
    const int lin = (xcd < r ? xcd * (q + 1) : r * (q + 1) + (xcd - r) * q) + idx;
    const int by = lin / gx, bx = lin - by * gx;
    const int rowBase = by * 256, colBase = bx * 128;

    f32x4 acc[4][4];
    #pragma unroll
    for (int m = 0; m < 4; m++)
        #pragma unroll
        for (int n = 0; n < 4; n++) acc[m][n] = 0.f;

    const u16* gApt[2];
    const u16* gBpt;
    #pragma unroll
    for (int i = 0; i < 2; i++) {
        int G = i * 512 + tid;
        int row = G >> 2, p = G & 3;
        int c = p ^ ((row >> 1) & 3);
        int grow = rowBase + row; if (grow > M - 1) grow = M - 1;
        gApt[i] = A + (size_t)grow * K + c * 8;
    }
    {
        int G = tid;
        int row = G >> 2, p = G & 3;
        int c = p ^ ((row >> 1) & 3);
        gBpt = W + (size_t)(colBase + row) * K + c * 8;
    }

    const int NT = K >> 5;
    auto STAGE = [&](int tt, int buf) {
        const int kb = tt << 5;
        u16* dA = lds + buf * 12288;
        u16* dB = dA + 8192;
        gload16(gApt[0] + kb, dA + (size_t)(w * 64) * 8);
        gload16(gApt[1] + kb, dA + (size_t)(512 + w * 64) * 8);
        gload16(gBpt + kb, dB + (size_t)(w * 64) * 8);
    };
    STAGE(0, 0);
    if (NT > 1) STAGE(1, 1);

    int cbuf = 0, sbuf = 2;
    for (int t = 0; t < NT; ++t) {
        if (t + 1 < NT) asm volatile("s_waitcnt vmcnt(3)" ::: "memory");
        else            asm volatile("s_waitcnt vmcnt(0)" ::: "memory");
        __builtin_amdgcn_s_barrier();
        __builtin_amdgcn_sched_barrier(0);
        if (t + 2 < NT) STAGE(t + 2, sbuf);

        const u16* Ab = lds + cbuf * 12288;
        const u16* Bb = Ab + 8192;
        const int c = l >> 4;
        bf16x8 av[4], bv[4];
        #pragma unroll
        for (int fr = 0; fr < 4; fr++) {
            int row = wm * 64 + fr * 16 + (l & 15);
            av[fr] = *(const bf16x8*)(Ab + row * 32 + ((c ^ ((row >> 1) & 3)) * 8));
        }
        #pragma unroll
        for (int fc = 0; fc < 4; fc++) {
            int col = wn * 64 + fc * 16 + (l & 15);
            bv[fc] = *(const bf16x8*)(Bb + col * 32 + ((c ^ ((col >> 1) & 3)) * 8));
        }
        __builtin_amdgcn_s_setprio(1);
        #pragma unroll
        for (int m = 0; m < 4; m++)
            #pragma unroll
            for (int n = 0; n < 4; n++)
                acc[m][n] = __builtin_amdgcn_mfma_f32_16x16x32_bf16(av[m], bv[n], acc[m][n], 0, 0, 0);
        __builtin_amdgcn_s_setprio(0);

        cbuf = (cbuf == 2) ? 0 : cbuf + 1;
        sbuf = (sbuf == 2) ? 0 : sbuf + 1;
    }
    __builtin_amdgcn_s_barrier();
    __builtin_amdgcn_sched_barrier(0);

    const int cc = colBase + wn * 64 + (l & 15);
    float bs4[4];
    #pragma unroll
    for (int n = 0; n < 4; n++) bs4[n] = bias[cc + n * 16];

    u16* WS = lds + w * 2048;
    #pragma unroll
    for (int hh = 0; hh < 2; hh++) {
        #pragma unroll
        for (int mi = 0; mi < 2; mi++) {
            #pragma unroll
            for (int n = 0; n < 4; n++) {
                int colv = n * 16 + (l & 15);
                #pragma unroll
                for (int reg = 0; reg < 4; reg++) {
                    int rowh = mi * 16 + (l >> 4) * 4 + reg;
                    float v = acc[hh * 2 + mi][n][reg] + bs4[n];
                    if (relu) v = fmaxf(v, 0.f);
                    WS[rowh * 64 + (colv ^ (((rowh >> 2) & 3) << 4))] = f2bf(v);
                }
            }
        }
        asm volatile("s_waitcnt lgkmcnt(0)" ::: "memory");
        __builtin_amdgcn_sched_barrier(0);
        #pragma unroll
        for (int j = 0; j < 4; j++) {
            int rowh = (l >> 3) + 8 * j;
            int col8 = (l & 7) * 8;
            int colx = col8 ^ (((rowh >> 2) & 3) << 4);
            uint4 v = *(const uint4*)(WS + rowh * 64 + colx);
            int grow = rowBase + wm * 64 + hh * 32 + rowh;
            if (grow < M) {
                int gcol = colBase + wn * 64 + col8;
                if (resb) {
                    uint4 rb = *(const uint4*)&resb[(size_t)grow * N + gcol];
                    v.x = addbf2(v.x, rb.x);
                    v.y = addbf2(v.y, rb.y);
                    v.z = addbf2(v.z, rb.z);
                    v.w = addbf2(v.w, rb.w);
                }
                *(uint4*)(Cb + (size_t)grow * N + gcol) = v;
            }
        }
        asm volatile("s_waitcnt lgkmcnt(0)" ::: "memory");
    }
}

__global__ __launch_bounds__(512, 4)
void mfma_gemm(const u16* __restrict__ A, const u16* __restrict__ W,
               const float* __restrict__ bias, const u16* __restrict__ resb,
               u16* __restrict__ Cb, int M, int K, int N, int relu, int gx)
{
    __shared__ u16 lds[36864];
    gemm_v4_body(lds, A, W, bias, resb, Cb, M, K, N, relu, gx,
                 gridDim.x, blockIdx.x);
}

// Dual-problem launch: blocks [0,n0) -> problem 0, [n0,n0+n1) -> problem 1.
__global__ __launch_bounds__(512, 4)
void mfma_gemm_dual(const u16* __restrict__ A0, const u16* __restrict__ W0,
                    const float* __restrict__ b0, u16* __restrict__ C0,
                    int M0, int K0, int N0, int gx0, int n0,
                    const u16* __restrict__ A1, const u16* __restrict__ W1,
                    const float* __restrict__ b1, u16* __restrict__ C1,
                    int M1, int K1, int N1, int gx1, int n1)
{
    __shared__ u16 lds[36864];
    if ((int)blockIdx.x < n0)
        gemm_v4_body(lds, A0, W0, b0, nullptr, C0, M0, K0, N0, 0, gx0,
                     n0, blockIdx.x);
    else
        gemm_v4_body(lds, A1, W1, b1, nullptr, C1, M1, K1, N1, 0, gx1,
                     n1, blockIdx.x - n0);
}

// ---------------------------------------------------------------------------
// Attention (bf16 in/out) with XCD-chunked block swizzle.
// ---------------------------------------------------------------------------
__global__ void attn_kernel(const u16* __restrict__ QKV, const u16* __restrict__ KVs,
                            u16* __restrict__ O)
{
    const int wv   = threadIdx.x >> 6;
    const int lane = threadIdx.x & 63;
    const int bswz = (blockIdx.x & 7) * (gridDim.x >> 3) + (blockIdx.x >> 3);
    const int b    = bswz * 4 + wv;
    const int h    = lane >> 3;
    const int d8   = lane & 7;
    const int n = b >> 10, pos = b & 1023;

    float q[8];
    ld8bf(QKV + (size_t)b * 1536 + h * 64 + d8 * 8, q);

    float sc[NSCALES];
    {
        float kk[8];
        ld8bf(QKV + (size_t)b * 1536 + 512 + h * 64 + d8 * 8, kk);
        float p = 0.f;
        #pragma unroll
        for (int j = 0; j < 8; j++) p += q[j] * kk[j];
        p += __shfl_xor(p, 1); p += __shfl_xor(p, 2); p += __shfl_xor(p, 4);
        sc[0] = p * 0.125f;
    }
    {
        int rowOff = 0;
        #pragma unroll
        for (int s = 1; s <= NLEVELS; s++) {
            int Ls = 1024 >> s;
            int row = rowOff + n * Ls + (pos >> s);
            float kk[8];
            ld8bf(KVs + (size_t)row * 1024 + h * 64 + d8 * 8, kk);
            float p = 0.f;
            #pragma unroll
            for (int j = 0; j < 8; j++) p += q[j] * kk[j];
            p += __shfl_xor(p, 1); p += __shfl_xor(p, 2); p += __shfl_xor(p, 4);
            sc[s] = p * 0.125f;
            rowOff += 16 * Ls;
        }
    }
    float m = sc[0];
    #pragma unroll
    for (int s = 1; s < NSCALES; s++) m = fmaxf(m, sc[s]);
    float sum = 0.f;
    #pragma unroll
    for (int s = 0; s < NSCALES; s++) { sc[s] = __expf(sc[s] - m); sum += sc[s]; }
    float inv = 1.f / sum;

    float o[8] = {};
    {
        float vv[8];
        ld8bf(QKV + (size_t)b * 1536 + 1024 + h * 64 + d8 * 8, vv);
        float a = sc[0] * inv;
        #pragma unroll
        for (int j = 0; j < 8; j++) o[j] += a * vv[j];
    }
    {
        int rowOff = 0;
        #pragma unroll
        for (int s = 1; s <= NLEVELS; s++) {
            int Ls = 1024 >> s;
            int row = rowOff + n * Ls + (pos >> s);
            float vv[8];
            ld8bf(KVs + (size_t)row * 1024 + 512 + h * 64 + d8 * 8, vv);
            float a = sc[s] * inv;
            #pragma unroll
            for (int j = 0; j < 8; j++) o[j] += a * vv[j];
            rowOff += 16 * Ls;
        }
    }
    uint4 pk;
    pk.x = (uint32_t)f2bf(o[0]) | ((uint32_t)f2bf(o[1]) << 16);
    pk.y = (uint32_t)f2bf(o[2]) | ((uint32_t)f2bf(o[3]) << 16);
    pk.z = (uint32_t)f2bf(o[4]) | ((uint32_t)f2bf(o[5]) << 16);
    pk.w = (uint32_t)f2bf(o[6]) | ((uint32_t)f2bf(o[7]) << 16);
    *(uint4*)(O + (size_t)b * 512 + h * 64 + d8 * 8) = pk;
}

// ---------------------------------------------------------------------------
// LayerNorm over E=512, bf16 input.
// ---------------------------------------------------------------------------
__global__ void ln_bf_kernel(const u16* __restrict__ in_bf,
                             const float* __restrict__ w, const float* __restrict__ b,
                             u16* __restrict__ out_bf, float* __restrict__ out_f)
{
    const int l = threadIdx.x & 63;
    const int row = blockIdx.x * 4 + (threadIdx.x >> 6);
    float v[8];
    ld8bf(in_bf + (size_t)row * EE + l * 8, v);
    float s = 0.f, s2 = 0.f;
    #pragma unroll
    for (int j = 0; j < 8; j++) { s += v[j]; s2 += v[j] * v[j]; }
    #pragma unroll
    for (int m = 1; m < 64; m <<= 1) { s += __shfl_xor(s, m); s2 += __shfl_xor(s2, m); }
    float mu  = s * (1.f / 512.f);
    float var = s2 * (1.f / 512.f) - mu * mu;
    float rs  = rsqrtf(var + 1e-5f);
    float4 w0 = *(const float4*)&w[l * 8], w1 = *(const float4*)&w[l * 8 + 4];
    float4 b0 = *(const float4*)&b[l * 8], b1 = *(const float4*)&b[l * 8 + 4];
    float o[8];
    o[0] = (v[0] - mu) * rs * w0.x + b0.x;
    o[1] = (v[1] - mu) * rs * w0.y + b0.y;
    o[2] = (v[2] - mu) * rs * w0.z + b0.z;
    o[3] = (v[3] - mu) * rs * w0.w + b0.w;
    o[4] = (v[4] - mu) * rs * w1.x + b1.x;
    o[5] = (v[5] - mu) * rs * w1.y + b1.y;
    o[6] = (v[6] - mu) * rs * w1.z + b1.z;
    o[7] = (v[7] - mu) * rs * w1.w + b1.w;
    if (out_bf) {
        uint4 pk;
        pk.x = (uint32_t)f2bf(o[0]) | ((uint32_t)f2bf(o[1]) << 16);
        pk.y = (uint32_t)f2bf(o[2]) | ((uint32_t)f2bf(o[3]) << 16);
        pk.z = (uint32_t)f2bf(o[4]) | ((uint32_t)f2bf(o[5]) << 16);
        pk.w = (uint32_t)f2bf(o[6]) | ((uint32_t)f2bf(o[7]) << 16);
        *(uint4*)(out_bf + (size_t)row * EE + l * 8) = pk;
    }
    if (out_f) {
        float* po = out_f + (size_t)row * EE + l * 8;
        *(float4*)po       = make_float4(o[0], o[1], o[2], o[3]);
        *(float4*)(po + 4) = make_float4(o[4], o[5], o[6], o[7]);
    }
}

// ---------------------------------------------------------------------------
extern "C" void kernel_launch(void* const* d_in, const int* in_sizes, int n_in,
                              void* d_out, int out_size, void* d_ws, size_t ws_size,
                              hipStream_t stream)
{
    const float* src        = (const float*)d_in[0];
    const float* conv_w     = (const float*)d_in[1];
    const float* conv_b     = (const float*)d_in[2];
    const float* in_proj_w  = (const float*)d_in[3];
    const float* in_proj_b  = (const float*)d_in[4];
    const float* out_proj_w = (const float*)d_in[5];
    const float* out_proj_b = (const float*)d_in[6];
    const float* ln1_w      = (const float*)d_in[7];
    const float* ln1_b      = (const float*)d_in[8];
    const float* ln2_w      = (const float*)d_in[9];
    const float* ln2_b      = (const float*)d_in[10];
    const float* w1         = (const float*)d_in[11];
    const float* b1         = (const float*)d_in[12];
    const float* w2         = (const float*)d_in[13];
    const float* b2         = (const float*)d_in[14];

    char*  wsb    = (char*)d_ws;
    float* out    = (float*)d_out;
    u16*   src_bf = (u16*)(wsb + B_SRCBF);
    u16*   lvl_bf = (u16*)(wsb + B_LVLBF);
    u16*   QKV    = (u16*)(wsb + B_QKV);
    u16*   KVs    = (u16*)(wsb + B_KVS);
    u16*   O_bf   = (u16*)(wsb + B_OBF);
    u16*   XPRE   = (u16*)(wsb + B_XPRE);
    u16*   OUTBF  = (u16*)(wsb + B_OUTBF);
    u16*   X_bf   = (u16*)(wsb + B_XBF);
    u16*   inw_bf = (u16*)(wsb + B_WBF);
    u16*   outw_bf= inw_bf + 786432;
    u16*   w1_bf  = outw_bf + 262144;
    u16*   w2_bf  = w1_bf + 1048576;
    u16*   cw_bf  = w2_bf + 1048576;
    u16*   FFH    = (u16*)(wsb + B_FFH);

    // 0) cast src + weights to bf16 (+ conv_w repack)
    cast_all_kernel<<<11344, 256, 0, stream>>>(src, in_proj_w, out_proj_w, w1, w2, conv_w,
                                               src_bf, inw_bf, outw_bf, w1_bf, w2_bf, cw_bf);

    // 1) conv pyramid
    conv_chain_kernel<<<NB * NHEADS * 4, 256, 0, stream>>>(src_bf, lvl_bf, cw_bf, conv_b);
    conv_tail_kernel<<<NB * NHEADS, 256, 0, stream>>>(lvl_bf, cw_bf, conv_b);

    // 2+3) QKV (16384x1536) and KVs (16368x1024) as ONE dual launch:
    //      blocks [0,768) -> QKV, [768,1280) -> KVs (tail backfill).
    mfma_gemm_dual<<<768 + 512, 512, 0, stream>>>(
        src_bf, inw_bf, in_proj_b, QKV, BROWS, EE, 1536, 12, 768,
        lvl_bf, inw_bf + (size_t)512 * 512, in_proj_b + 512, KVs,
        16368, EE, 1024, 8, 512);

    // 4) attention -> O_bf  (XCD-chunked block swizzle)
    attn_kernel<<<BROWS / 4, 256, 0, stream>>>(QKV, KVs, O_bf);

    // 5) XPRE = out_proj (16384 x 512, K=512): v4, grid 256
    mfma_gemm<<<64 * 4, 512, 0, stream>>>(
        O_bf, outw_bf, out_proj_b, nullptr, XPRE, BROWS, EE, EE, 0, 4);

    // 6) LN1: X_bf = LN(XPRE)
    ln_bf_kernel<<<BROWS / 4, 256, 0, stream>>>(XPRE, ln1_w, ln1_b, X_bf, nullptr);

    // 7) FFN1 (16384 x 2048, K=512): v4, grid 64x16
    mfma_gemm<<<64 * 16, 512, 0, stream>>>(
        X_bf, w1_bf, b1, nullptr, FFH, BROWS, EE, DFF, 1, 16);

    // 8) FFN2 + residual (16384 x 512, K=2048): v4, grid 256
    mfma_gemm<<<64 * 4, 512, 0, stream>>>(
        FFH, w2_bf, b2, X_bf, OUTBF, BROWS, DFF, EE, 0, 4);

    // 9) LN2: out = LN(OUTBF)
    ln_bf_kernel<<<BROWS / 4, 256, 0, stream>>>(OUTBF, ln2_w, ln2_b, nullptr, out);
}